// Round 5
// baseline (314.834 us; speedup 1.0000x reference)
//
#include <hip/hip_runtime.h>

#define DIM 64
#define NBUCK 256
#define BSHIFT 9
#define BCAP 12288
#define CHUNK 4096

template <int CTRL>
__device__ __forceinline__ float qperm(float v) {
    return __int_as_float(__builtin_amdgcn_update_dpp(
        0, __float_as_int(v), CTRL, 0xF, 0xF, true));
}

// Per-lane-row GEMM: lane owns one row; weights are wave-uniform -> SGPR
// broadcast (v_fmac v,s,v : 1 VALU op per FMA, no readlane).
// h = x @ Wl^T + b.  64 rows per wave.
__global__ __launch_bounds__(256, 3) void gemm64_kernel(
    const float* __restrict__ in, const float* __restrict__ W,
    const float* __restrict__ bias, float* __restrict__ out, int nrows)
{
    const int lane = threadIdx.x & 63;
    const int wid  = blockIdx.x * (blockDim.x >> 6) + (threadIdx.x >> 6);
    const int r    = wid * 64 + lane;
    const bool alive = r < nrows;

    float vin[DIM];
    {
        const float* rp = in + (size_t)r * DIM;
#pragma unroll
        for (int j4 = 0; j4 < DIM / 4; ++j4) {
            float4 t = make_float4(0.f, 0.f, 0.f, 0.f);
            if (alive) t = *reinterpret_cast<const float4*>(rp + 4 * j4);
            vin[4*j4+0]=t.x; vin[4*j4+1]=t.y; vin[4*j4+2]=t.z; vin[4*j4+3]=t.w;
        }
    }

    float z[DIM];
#pragma unroll
    for (int o = 0; o < DIM; ++o) {
        float a0 = bias[o], a1 = 0.f, a2 = 0.f, a3 = 0.f;
#pragma unroll
        for (int j = 0; j < DIM; j += 4) {
            a0 = fmaf(W[o*DIM+j+0], vin[j+0], a0);
            a1 = fmaf(W[o*DIM+j+1], vin[j+1], a1);
            a2 = fmaf(W[o*DIM+j+2], vin[j+2], a2);
            a3 = fmaf(W[o*DIM+j+3], vin[j+3], a3);
        }
        z[o] = (a0 + a1) + (a2 + a3);
    }

    if (alive) {
        float* op = out + (size_t)r * DIM;
#pragma unroll
        for (int j4 = 0; j4 < DIM / 4; ++j4)
            *reinterpret_cast<float4*>(op + 4 * j4) =
                make_float4(z[4*j4+0], z[4*j4+1], z[4*j4+2], z[4*j4+3]);
    }
}

// fused tail, per-lane-row: z = (1+eps)*h + aggr@Wh^T+bh ;
// hid = relu(z@W1^T+b1) ; out = hid@W2^T+b2
__global__ __launch_bounds__(256, 2) void tail_kernel(
    const float* __restrict__ aggr, const float* __restrict__ h,
    const float* __restrict__ Wh, const float* __restrict__ bh,
    const float* __restrict__ W1, const float* __restrict__ b1,
    const float* __restrict__ W2, const float* __restrict__ b2,
    const float* __restrict__ eps, float* __restrict__ out, int nrows)
{
    const int lane = threadIdx.x & 63;
    const int wid  = blockIdx.x * (blockDim.x >> 6) + (threadIdx.x >> 6);
    const int r    = wid * 64 + lane;
    const bool alive = r < nrows;
    const float escale = 1.0f + eps[0];

    float vin[DIM], vh[DIM];
    {
        const float* ap = aggr + (size_t)r * DIM;
        const float* hp = h + (size_t)r * DIM;
#pragma unroll
        for (int j4 = 0; j4 < DIM / 4; ++j4) {
            float4 t = make_float4(0.f, 0.f, 0.f, 0.f);
            float4 u = make_float4(0.f, 0.f, 0.f, 0.f);
            if (alive) {
                t = *reinterpret_cast<const float4*>(ap + 4 * j4);
                u = *reinterpret_cast<const float4*>(hp + 4 * j4);
            }
            vin[4*j4+0]=t.x; vin[4*j4+1]=t.y; vin[4*j4+2]=t.z; vin[4*j4+3]=t.w;
            vh[4*j4+0]=u.x; vh[4*j4+1]=u.y; vh[4*j4+2]=u.z; vh[4*j4+3]=u.w;
        }
    }

    float z[DIM];
#pragma unroll
    for (int o = 0; o < DIM; ++o) {
        float a0 = bh[o], a1 = 0.f, a2 = 0.f, a3 = 0.f;
#pragma unroll
        for (int j = 0; j < DIM; j += 4) {
            a0 = fmaf(Wh[o*DIM+j+0], vin[j+0], a0);
            a1 = fmaf(Wh[o*DIM+j+1], vin[j+1], a1);
            a2 = fmaf(Wh[o*DIM+j+2], vin[j+2], a2);
            a3 = fmaf(Wh[o*DIM+j+3], vin[j+3], a3);
        }
        z[o] = fmaf(escale, vh[o], (a0 + a1) + (a2 + a3));
    }

    float hid[DIM];
#pragma unroll
    for (int o = 0; o < DIM; ++o) {
        float a0 = b1[o], a1 = 0.f, a2 = 0.f, a3 = 0.f;
#pragma unroll
        for (int j = 0; j < DIM; j += 4) {
            a0 = fmaf(W1[o*DIM+j+0], z[j+0], a0);
            a1 = fmaf(W1[o*DIM+j+1], z[j+1], a1);
            a2 = fmaf(W1[o*DIM+j+2], z[j+2], a2);
            a3 = fmaf(W1[o*DIM+j+3], z[j+3], a3);
        }
        hid[o] = fmaxf((a0 + a1) + (a2 + a3), 0.f);
    }

    float res[DIM];
#pragma unroll
    for (int o = 0; o < DIM; ++o) {
        float a0 = b2[o], a1 = 0.f, a2 = 0.f, a3 = 0.f;
#pragma unroll
        for (int j = 0; j < DIM; j += 4) {
            a0 = fmaf(W2[o*DIM+j+0], hid[j+0], a0);
            a1 = fmaf(W2[o*DIM+j+1], hid[j+1], a1);
            a2 = fmaf(W2[o*DIM+j+2], hid[j+2], a2);
            a3 = fmaf(W2[o*DIM+j+3], hid[j+3], a3);
        }
        res[o] = (a0 + a1) + (a2 + a3);
    }

    if (alive) {
        float* op = out + (size_t)r * DIM;
#pragma unroll
        for (int j4 = 0; j4 < DIM / 4; ++j4)
            *reinterpret_cast<float4*>(op + 4 * j4) =
                make_float4(res[4*j4+0], res[4*j4+1], res[4*j4+2], res[4*j4+3]);
    }
}

__global__ __launch_bounds__(256) void zero256_kernel(int* __restrict__ p) {
    p[threadIdx.x] = 0;
}

__device__ __forceinline__ int wave_incl_scan(int v, int lane) {
#pragma unroll
    for (int off = 1; off < 64; off <<= 1) {
        int t = __shfl_up(v, (unsigned)off, 64);
        if (lane >= off) v += t;
    }
    return v;
}

// Bin edges into 256 buckets (bucket = row>>9). record = col | sign<<17 | (row&511)<<18
__global__ __launch_bounds__(256) void bin_kernel(
    const int* __restrict__ ei, const int* __restrict__ sgn,
    int* __restrict__ bcursor, int* __restrict__ records, int E)
{
    const int tid = threadIdx.x;
    const int base = blockIdx.x * CHUNK;
    __shared__ int lcnt[NBUCK];
    __shared__ int lbase[NBUCK];
    lcnt[tid] = 0;
    __syncthreads();
    const int lim = min(CHUNK, E - base);
    for (int k = tid; k < lim; k += 256)
        atomicAdd(&lcnt[ei[base + k] >> BSHIFT], 1);
    __syncthreads();
    const int c = lcnt[tid];
    lbase[tid] = c ? atomicAdd(&bcursor[tid], c) : 0;
    lcnt[tid] = 0;
    __syncthreads();
    for (int k = tid; k < lim; k += 256) {
        const int e = base + k;
        const int r  = ei[e];
        const int cc = ei[E + e];
        const int s  = sgn[e];
        const int b  = r >> BSHIFT;
        const int idx = lbase[b] + atomicAdd(&lcnt[b], 1);
        if (idx < BCAP)
            records[b * BCAP + idx] = cc | (s << 17) | ((r & 511) << 18);
    }
}

__global__ __launch_bounds__(256) void scan256_kernel(
    const int* __restrict__ bcursor, int* __restrict__ csrb,
    int* __restrict__ offsets, int* __restrict__ edata, int N, int E)
{
    const int tid = threadIdx.x, lane = tid & 63, w = tid >> 6;
    const int v = min(bcursor[tid], BCAP);
    const int inc = wave_incl_scan(v, lane);
    __shared__ int wtot[4];
    if (lane == 63) wtot[w] = inc;
    __syncthreads();
    int add = 0;
#pragma unroll
    for (int i = 0; i < 4; ++i)
        if (i < w) add += wtot[i];
    csrb[tid] = add + inc - v;
    if (tid == 0) { offsets[N] = E; edata[E] = 0; }
}

__global__ __launch_bounds__(256) void build_kernel(
    const int* __restrict__ records, const int* __restrict__ bcursor,
    const int* __restrict__ csrb, int* __restrict__ offsets,
    int* __restrict__ edata, int N)
{
    const int b = blockIdx.x;
    const int tid = threadIdx.x, lane = tid & 63, w = tid >> 6;
    const int nbase = b << BSHIFT;
    const int nn = min(512, N - nbase);
    if (nn <= 0) return;
    const int cnt = min(bcursor[b], BCAP);
    const int base_csr = csrb[b];
    const int* rec = records + b * BCAP;

    __shared__ int ncnt[512];
    __shared__ int wtot[8];
    __shared__ int stag[BCAP];

    ncnt[tid] = 0; ncnt[256 + tid] = 0;
    __syncthreads();
    for (int i = tid; i < cnt; i += 256)
        atomicAdd(&ncnt[rec[i] >> 18], 1);
    __syncthreads();
    const int v0 = ncnt[tid], v1 = ncnt[256 + tid];
    const int i0 = wave_incl_scan(v0, lane);
    if (lane == 63) wtot[w] = i0;
    const int i1 = wave_incl_scan(v1, lane);
    if (lane == 63) wtot[4 + w] = i1;
    __syncthreads();
    int a0 = 0, a1 = 0;
#pragma unroll
    for (int i = 0; i < 4; ++i) {
        if (i < w) { a0 += wtot[i]; a1 += wtot[4 + i]; }
    }
    const int half = wtot[0] + wtot[1] + wtot[2] + wtot[3];
    const int e0 = a0 + i0 - v0;
    const int e1 = half + a1 + i1 - v1;
    if (tid < nn)       offsets[nbase + tid]       = base_csr + e0;
    if (256 + tid < nn) offsets[nbase + 256 + tid] = base_csr + e1;
    __syncthreads();
    ncnt[tid] = e0; ncnt[256 + tid] = e1;
    __syncthreads();
    for (int i = tid; i < cnt; i += 256) {
        const int rcd = rec[i];
        const int p = atomicAdd(&ncnt[rcd >> 18], 1);
        stag[p] = (rcd & 0x1FFFF) | (((rcd >> 17) & 1) << 20);
    }
    __syncthreads();
    for (int i = tid; i < cnt; i += 256)
        edata[base_csr + i] = stag[i];
}

// 4 nodes per wave; 16 lanes per node; lane holds float4 of the feature row.
__global__ __launch_bounds__(256) void attn_kernel(
    const float* __restrict__ h, const int* __restrict__ offsets,
    const int* __restrict__ edata, const float* __restrict__ sign_tab,
    float* __restrict__ aggr, int n)
{
    const int lane = threadIdx.x & 63;
    const int gl   = lane & 15;
    const int node = blockIdx.x * 16 + ((threadIdx.x >> 6) << 2) + (lane >> 4);
    const bool alive = node < n;

    int beg = 0, deg = 0;
    if (alive) {
        beg = offsets[node];
        deg = offsets[node + 1] - beg;
    }
    float4 hi = make_float4(0.f, 0.f, 0.f, 0.f);
    if (alive) hi = *reinterpret_cast<const float4*>(h + (size_t)node * DIM + gl * 4);

    const float4 s0 = *reinterpret_cast<const float4*>(sign_tab + (gl & 3) * 4);
    const float4 s1 = *reinterpret_cast<const float4*>(sign_tab + 16 + (gl & 3) * 4);
    const float4 hs0 = make_float4(hi.x * s0.x, hi.y * s0.y, hi.z * s0.z, hi.w * s0.w);
    const float4 hs1 = make_float4(hi.x * s1.x, hi.y * s1.y, hi.z * s1.z, hi.w * s1.w);

    const int degm1 = deg - 1;
    int maxdeg = max(deg, __shfl_xor(deg, 16, 64));
    maxdeg = max(maxdeg, __shfl_xor(maxdeg, 32, 64));

    float den = 0.f;
    float4 msg = make_float4(0.f, 0.f, 0.f, 0.f);

    for (int e = 0; e < maxdeg; e += 4) {
        int idx[4], pk[4];
#pragma unroll
        for (int u = 0; u < 4; ++u) idx[u] = max(0, min(e + u, degm1));
#pragma unroll
        for (int u = 0; u < 4; ++u) pk[u] = edata[beg + idx[u]];

        float4 hj[4];
#pragma unroll
        for (int u = 0; u < 4; ++u) {
            const int col = pk[u] & 0xFFFFF;
            hj[u] = *reinterpret_cast<const float4*>(h + (size_t)col * DIM + gl * 4);
        }

        float sc[4];
#pragma unroll
        for (int u = 0; u < 4; ++u) {
            const float4 w = (pk[u] >> 20) ? hs1 : hs0;
            float s = w.x * hj[u].x;
            s = fmaf(w.y, hj[u].y, s);
            s = fmaf(w.z, hj[u].z, s);
            s = fmaf(w.w, hj[u].w, s);
            sc[u] = s;
        }
#pragma unroll
        for (int u = 0; u < 4; ++u) sc[u] += qperm<0xB1>(sc[u]);
#pragma unroll
        for (int u = 0; u < 4; ++u) sc[u] += qperm<0x4E>(sc[u]);

#pragma unroll
        for (int u = 0; u < 4; ++u) {
            const float ex = (e + u < deg) ? __expf(sc[u]) : 0.f;
            den += ex;
            msg.x = fmaf(ex, hj[u].x, msg.x);
            msg.y = fmaf(ex, hj[u].y, msg.y);
            msg.z = fmaf(ex, hj[u].z, msg.z);
            msg.w = fmaf(ex, hj[u].w, msg.w);
        }
    }

    if (alive) {
        const float inv = 1.0f / (den + 1e-16f);
        float4 o = make_float4(msg.x * inv, msg.y * inv, msg.z * inv, msg.w * inv);
        *reinterpret_cast<float4*>(aggr + (size_t)node * DIM + gl * 4) = o;
    }
}

extern "C" void kernel_launch(void* const* d_in, const int* in_sizes, int n_in,
                              void* d_out, int out_size, void* d_ws, size_t ws_size,
                              hipStream_t stream) {
    const float* x        = (const float*)d_in[0];
    const int*   ei       = (const int*)d_in[1];
    const int*   esign    = (const int*)d_in[2];
    const float* Wl_w     = (const float*)d_in[3];
    const float* Wl_b     = (const float*)d_in[4];
    const float* sign_tab = (const float*)d_in[5];
    const float* Wh_w     = (const float*)d_in[6];
    const float* Wh_b     = (const float*)d_in[7];
    const float* w1       = (const float*)d_in[8];
    const float* b1       = (const float*)d_in[9];
    const float* w2       = (const float*)d_in[10];
    const float* b2       = (const float*)d_in[11];
    const float* eps      = (const float*)d_in[12];
    float* out = (float*)d_out;

    const int N = in_sizes[0] / DIM;
    const int E = in_sizes[2];

    float* h       = (float*)d_ws;
    float* aggr    = h + (size_t)N * DIM;
    int*   records = (int*)aggr;                 // alias: dead before attn writes aggr
    int*   edata   = (int*)(aggr + (size_t)N * DIM);
    int*   bcursor = edata + (E + 1);
    int*   csrb    = bcursor + NBUCK;
    int*   offsets = csrb + NBUCK;               // N+1 ints

    const int rowblocks = (N + 255) / 256;       // 64 rows per wave, 4 waves/block

    // h = x @ Wl^T + Wl_b
    gemm64_kernel<<<rowblocks, 256, 0, stream>>>(x, Wl_w, Wl_b, h, N);

    // bucketed counting-sort CSR build
    zero256_kernel<<<1, 256, 0, stream>>>(bcursor);
    bin_kernel<<<(E + CHUNK - 1) / CHUNK, 256, 0, stream>>>(ei, esign, bcursor, records, E);
    scan256_kernel<<<1, 256, 0, stream>>>(bcursor, csrb, offsets, edata, N, E);
    build_kernel<<<NBUCK, 256, 0, stream>>>(records, bcursor, csrb, offsets, edata, N);

    // segment softmax + aggregation: 4 nodes/wave, 16 nodes/block
    attn_kernel<<<(N + 15) / 16, 256, 0, stream>>>(h, offsets, edata, sign_tab, aggr, N);

    // fused tail: z -> relu mlp -> out
    tail_kernel<<<rowblocks, 256, 0, stream>>>(aggr, h, Wh_w, Wh_b, w1, b1, w2, b2, eps, out, N);
}

// Round 6
// 220.199 us; speedup vs baseline: 1.4298x; 1.4298x over previous
//
#include <hip/hip_runtime.h>

#define DIM 64
#define NBUCK 256
#define BSHIFT 9
#define BCAP 12288
#define CHUNK 4096

typedef __attribute__((ext_vector_type(2))) float f32x2;

__device__ __forceinline__ float rdlane(float v, int l) {
    return __int_as_float(__builtin_amdgcn_readlane(__float_as_int(v), l));
}

// acc.lo += blo*w.lo ; acc.hi += bhi*w.hi   (1 VALU issue for 2 FMAs)
// blo/bhi are wave-uniform (readlane results) -> SGPR pair operand.
__device__ __forceinline__ void pkfma(f32x2& acc, float blo, float bhi, f32x2 w) {
    f32x2 p; p.x = blo; p.y = bhi;
    asm("v_pk_fma_f32 %0, %1, %2, %0" : "+v"(acc) : "s"(p), "v"(w));
}

template <int CTRL>
__device__ __forceinline__ float qperm(float v) {
    return __int_as_float(__builtin_amdgcn_update_dpp(
        0, __float_as_int(v), CTRL, 0xF, 0xF, true));
}

// lane o computes dot(W_row_o, src_row) where src_row is distributed one
// element per lane; broadcast via readlane pairs, accumulate packed.
template <bool RELU>
__device__ __forceinline__ float dot64_bcast(const f32x2* __restrict__ w,
                                             float src, float bias0) {
    f32x2 A0 = {bias0, 0.f}, A1 = {0.f, 0.f}, A2 = {0.f, 0.f}, A3 = {0.f, 0.f};
#pragma unroll
    for (int jp = 0; jp < 32; jp += 4) {
        pkfma(A0, rdlane(src, 2*jp + 0), rdlane(src, 2*jp + 1), w[jp + 0]);
        pkfma(A1, rdlane(src, 2*jp + 2), rdlane(src, 2*jp + 3), w[jp + 1]);
        pkfma(A2, rdlane(src, 2*jp + 4), rdlane(src, 2*jp + 5), w[jp + 2]);
        pkfma(A3, rdlane(src, 2*jp + 6), rdlane(src, 2*jp + 7), w[jp + 3]);
    }
    const float s = ((A0.x + A0.y) + (A1.x + A1.y)) + ((A2.x + A2.y) + (A3.x + A3.y));
    return RELU ? fmaxf(s, 0.f) : s;
}

// h = x @ Wl^T + b : lane o holds W row o in VGPRs; row broadcast by readlane.
__global__ __launch_bounds__(256, 3) void gemm64_kernel(
    const float* __restrict__ in, const float* __restrict__ W,
    const float* __restrict__ bias, float* __restrict__ out, int nrows)
{
    const int lane = threadIdx.x & 63;
    const int wid  = blockIdx.x * (blockDim.x >> 6) + (threadIdx.x >> 6);
    const int nwav = gridDim.x * (blockDim.x >> 6);

    f32x2 wl[32];
#pragma unroll
    for (int j4 = 0; j4 < 16; ++j4) {
        const float4 t = *reinterpret_cast<const float4*>(W + lane * DIM + j4 * 4);
        wl[2*j4]     = (f32x2){t.x, t.y};
        wl[2*j4 + 1] = (f32x2){t.z, t.w};
    }
    const float b = bias[lane];

    int r = wid;
    if (r >= nrows) return;
    float vx = in[(size_t)r * DIM + lane];

    while (r < nrows) {
        const int rn = r + nwav;
        float vxn = 0.f;
        if (rn < nrows) vxn = in[(size_t)rn * DIM + lane];
        out[(size_t)r * DIM + lane] = dot64_bcast<false>(wl, vx, b);
        vx = vxn;
        r = rn;
    }
}

// fused tail: z = (1+eps)*h + aggr@Wh^T+bh ; hid = relu(z@W1^T+b1) ; out = hid@W2^T+b2
__global__ __launch_bounds__(256, 2) void tail_kernel(
    const float* __restrict__ aggr, const float* __restrict__ h,
    const float* __restrict__ Wh, const float* __restrict__ bh,
    const float* __restrict__ W1, const float* __restrict__ b1,
    const float* __restrict__ W2, const float* __restrict__ b2,
    const float* __restrict__ eps, float* __restrict__ out, int nrows)
{
    const int lane = threadIdx.x & 63;
    const int wid  = blockIdx.x * (blockDim.x >> 6) + (threadIdx.x >> 6);
    const int nwav = gridDim.x * (blockDim.x >> 6);

    f32x2 wh[32], wa[32], wb[32];
#pragma unroll
    for (int j4 = 0; j4 < 16; ++j4) {
        float4 t;
        t = *reinterpret_cast<const float4*>(Wh + lane * DIM + j4 * 4);
        wh[2*j4] = (f32x2){t.x, t.y}; wh[2*j4+1] = (f32x2){t.z, t.w};
        t = *reinterpret_cast<const float4*>(W1 + lane * DIM + j4 * 4);
        wa[2*j4] = (f32x2){t.x, t.y}; wa[2*j4+1] = (f32x2){t.z, t.w};
        t = *reinterpret_cast<const float4*>(W2 + lane * DIM + j4 * 4);
        wb[2*j4] = (f32x2){t.x, t.y}; wb[2*j4+1] = (f32x2){t.z, t.w};
    }
    const float bhv = bh[lane], b1v = b1[lane], b2v = b2[lane];
    const float escale = 1.0f + eps[0];

    int r = wid;
    if (r >= nrows) return;
    float va = aggr[(size_t)r * DIM + lane];
    float vh = h[(size_t)r * DIM + lane];

    while (r < nrows) {
        const int rn = r + nwav;
        float van = 0.f, vhn = 0.f;
        if (rn < nrows) {
            van = aggr[(size_t)rn * DIM + lane];
            vhn = h[(size_t)rn * DIM + lane];
        }
        float z = dot64_bcast<false>(wh, va, bhv);
        z = fmaf(escale, vh, z);
        const float hid = dot64_bcast<true>(wa, z, b1v);
        const float res = dot64_bcast<false>(wb, hid, b2v);
        out[(size_t)r * DIM + lane] = res;
        va = van; vh = vhn;
        r = rn;
    }
}

__global__ __launch_bounds__(256) void zero256_kernel(int* __restrict__ p) {
    p[threadIdx.x] = 0;
}

__device__ __forceinline__ int wave_incl_scan(int v, int lane) {
#pragma unroll
    for (int off = 1; off < 64; off <<= 1) {
        int t = __shfl_up(v, (unsigned)off, 64);
        if (lane >= off) v += t;
    }
    return v;
}

// Bin edges into 256 buckets (bucket = row>>9). record = col | sign<<17 | (row&511)<<18
__global__ __launch_bounds__(256) void bin_kernel(
    const int* __restrict__ ei, const int* __restrict__ sgn,
    int* __restrict__ bcursor, int* __restrict__ records, int E)
{
    const int tid = threadIdx.x;
    const int base = blockIdx.x * CHUNK;
    __shared__ int lcnt[NBUCK];
    __shared__ int lbase[NBUCK];
    lcnt[tid] = 0;
    __syncthreads();
    const int lim = min(CHUNK, E - base);
    for (int k = tid; k < lim; k += 256)
        atomicAdd(&lcnt[ei[base + k] >> BSHIFT], 1);
    __syncthreads();
    const int c = lcnt[tid];
    lbase[tid] = c ? atomicAdd(&bcursor[tid], c) : 0;
    lcnt[tid] = 0;
    __syncthreads();
    for (int k = tid; k < lim; k += 256) {
        const int e = base + k;
        const int r  = ei[e];
        const int cc = ei[E + e];
        const int s  = sgn[e];
        const int b  = r >> BSHIFT;
        const int idx = lbase[b] + atomicAdd(&lcnt[b], 1);
        if (idx < BCAP)
            records[b * BCAP + idx] = cc | (s << 17) | ((r & 511) << 18);
    }
}

__global__ __launch_bounds__(256) void scan256_kernel(
    const int* __restrict__ bcursor, int* __restrict__ csrb,
    int* __restrict__ offsets, int* __restrict__ edata, int N, int E)
{
    const int tid = threadIdx.x, lane = tid & 63, w = tid >> 6;
    const int v = min(bcursor[tid], BCAP);
    const int inc = wave_incl_scan(v, lane);
    __shared__ int wtot[4];
    if (lane == 63) wtot[w] = inc;
    __syncthreads();
    int add = 0;
#pragma unroll
    for (int i = 0; i < 4; ++i)
        if (i < w) add += wtot[i];
    csrb[tid] = add + inc - v;
    if (tid == 0) { offsets[N] = E; edata[E] = 0; }
}

__global__ __launch_bounds__(256) void build_kernel(
    const int* __restrict__ records, const int* __restrict__ bcursor,
    const int* __restrict__ csrb, int* __restrict__ offsets,
    int* __restrict__ edata, int N)
{
    const int b = blockIdx.x;
    const int tid = threadIdx.x, lane = tid & 63, w = tid >> 6;
    const int nbase = b << BSHIFT;
    const int nn = min(512, N - nbase);
    if (nn <= 0) return;
    const int cnt = min(bcursor[b], BCAP);
    const int base_csr = csrb[b];
    const int* rec = records + b * BCAP;

    __shared__ int ncnt[512];
    __shared__ int wtot[8];
    __shared__ int stag[BCAP];

    ncnt[tid] = 0; ncnt[256 + tid] = 0;
    __syncthreads();
    for (int i = tid; i < cnt; i += 256)
        atomicAdd(&ncnt[rec[i] >> 18], 1);
    __syncthreads();
    const int v0 = ncnt[tid], v1 = ncnt[256 + tid];
    const int i0 = wave_incl_scan(v0, lane);
    if (lane == 63) wtot[w] = i0;
    const int i1 = wave_incl_scan(v1, lane);
    if (lane == 63) wtot[4 + w] = i1;
    __syncthreads();
    int a0 = 0, a1 = 0;
#pragma unroll
    for (int i = 0; i < 4; ++i) {
        if (i < w) { a0 += wtot[i]; a1 += wtot[4 + i]; }
    }
    const int half = wtot[0] + wtot[1] + wtot[2] + wtot[3];
    const int e0 = a0 + i0 - v0;
    const int e1 = half + a1 + i1 - v1;
    if (tid < nn)       offsets[nbase + tid]       = base_csr + e0;
    if (256 + tid < nn) offsets[nbase + 256 + tid] = base_csr + e1;
    __syncthreads();
    ncnt[tid] = e0; ncnt[256 + tid] = e1;
    __syncthreads();
    for (int i = tid; i < cnt; i += 256) {
        const int rcd = rec[i];
        const int p = atomicAdd(&ncnt[rcd >> 18], 1);
        stag[p] = (rcd & 0x1FFFF) | (((rcd >> 17) & 1) << 20);
    }
    __syncthreads();
    for (int i = tid; i < cnt; i += 256)
        edata[base_csr + i] = stag[i];
}

// 4 nodes per wave; 16 lanes per node; lane holds float4 of the feature row.
__global__ __launch_bounds__(256) void attn_kernel(
    const float* __restrict__ h, const int* __restrict__ offsets,
    const int* __restrict__ edata, const float* __restrict__ sign_tab,
    float* __restrict__ aggr, int n)
{
    const int lane = threadIdx.x & 63;
    const int gl   = lane & 15;
    const int node = blockIdx.x * 16 + ((threadIdx.x >> 6) << 2) + (lane >> 4);
    const bool alive = node < n;

    int beg = 0, deg = 0;
    if (alive) {
        beg = offsets[node];
        deg = offsets[node + 1] - beg;
    }
    float4 hi = make_float4(0.f, 0.f, 0.f, 0.f);
    if (alive) hi = *reinterpret_cast<const float4*>(h + (size_t)node * DIM + gl * 4);

    const float4 s0 = *reinterpret_cast<const float4*>(sign_tab + (gl & 3) * 4);
    const float4 s1 = *reinterpret_cast<const float4*>(sign_tab + 16 + (gl & 3) * 4);
    const float4 hs0 = make_float4(hi.x * s0.x, hi.y * s0.y, hi.z * s0.z, hi.w * s0.w);
    const float4 hs1 = make_float4(hi.x * s1.x, hi.y * s1.y, hi.z * s1.z, hi.w * s1.w);

    const int degm1 = deg - 1;
    int maxdeg = max(deg, __shfl_xor(deg, 16, 64));
    maxdeg = max(maxdeg, __shfl_xor(maxdeg, 32, 64));

    float den = 0.f;
    float4 msg = make_float4(0.f, 0.f, 0.f, 0.f);

    for (int e = 0; e < maxdeg; e += 4) {
        int idx[4], pk[4];
#pragma unroll
        for (int u = 0; u < 4; ++u) idx[u] = max(0, min(e + u, degm1));
#pragma unroll
        for (int u = 0; u < 4; ++u) pk[u] = edata[beg + idx[u]];

        float4 hj[4];
#pragma unroll
        for (int u = 0; u < 4; ++u) {
            const int col = pk[u] & 0xFFFFF;
            hj[u] = *reinterpret_cast<const float4*>(h + (size_t)col * DIM + gl * 4);
        }

        float sc[4];
#pragma unroll
        for (int u = 0; u < 4; ++u) {
            const float4 w = (pk[u] >> 20) ? hs1 : hs0;
            float s = w.x * hj[u].x;
            s = fmaf(w.y, hj[u].y, s);
            s = fmaf(w.z, hj[u].z, s);
            s = fmaf(w.w, hj[u].w, s);
            sc[u] = s;
        }
#pragma unroll
        for (int u = 0; u < 4; ++u) sc[u] += qperm<0xB1>(sc[u]);
#pragma unroll
        for (int u = 0; u < 4; ++u) sc[u] += qperm<0x4E>(sc[u]);

#pragma unroll
        for (int u = 0; u < 4; ++u) {
            const float ex = (e + u < deg) ? __expf(sc[u]) : 0.f;
            den += ex;
            msg.x = fmaf(ex, hj[u].x, msg.x);
            msg.y = fmaf(ex, hj[u].y, msg.y);
            msg.z = fmaf(ex, hj[u].z, msg.z);
            msg.w = fmaf(ex, hj[u].w, msg.w);
        }
    }

    if (alive) {
        const float inv = 1.0f / (den + 1e-16f);
        float4 o = make_float4(msg.x * inv, msg.y * inv, msg.z * inv, msg.w * inv);
        *reinterpret_cast<float4*>(aggr + (size_t)node * DIM + gl * 4) = o;
    }
}

extern "C" void kernel_launch(void* const* d_in, const int* in_sizes, int n_in,
                              void* d_out, int out_size, void* d_ws, size_t ws_size,
                              hipStream_t stream) {
    const float* x        = (const float*)d_in[0];
    const int*   ei       = (const int*)d_in[1];
    const int*   esign    = (const int*)d_in[2];
    const float* Wl_w     = (const float*)d_in[3];
    const float* Wl_b     = (const float*)d_in[4];
    const float* sign_tab = (const float*)d_in[5];
    const float* Wh_w     = (const float*)d_in[6];
    const float* Wh_b     = (const float*)d_in[7];
    const float* w1       = (const float*)d_in[8];
    const float* b1       = (const float*)d_in[9];
    const float* w2       = (const float*)d_in[10];
    const float* b2       = (const float*)d_in[11];
    const float* eps      = (const float*)d_in[12];
    float* out = (float*)d_out;

    const int N = in_sizes[0] / DIM;
    const int E = in_sizes[2];

    float* h       = (float*)d_ws;
    float* aggr    = h + (size_t)N * DIM;
    int*   records = (int*)aggr;                 // alias: dead before attn writes aggr
    int*   edata   = (int*)(aggr + (size_t)N * DIM);
    int*   bcursor = edata + (E + 1);
    int*   csrb    = bcursor + NBUCK;
    int*   offsets = csrb + NBUCK;               // N+1 ints

    // h = x @ Wl^T + Wl_b
    gemm64_kernel<<<1536, 256, 0, stream>>>(x, Wl_w, Wl_b, h, N);

    // bucketed counting-sort CSR build
    zero256_kernel<<<1, 256, 0, stream>>>(bcursor);
    bin_kernel<<<(E + CHUNK - 1) / CHUNK, 256, 0, stream>>>(ei, esign, bcursor, records, E);
    scan256_kernel<<<1, 256, 0, stream>>>(bcursor, csrb, offsets, edata, N, E);
    build_kernel<<<NBUCK, 256, 0, stream>>>(records, bcursor, csrb, offsets, edata, N);

    // segment softmax + aggregation: 4 nodes/wave, 16 nodes/block
    attn_kernel<<<(N + 15) / 16, 256, 0, stream>>>(h, offsets, edata, sign_tab, aggr, N);

    // fused tail: z -> relu mlp -> out
    tail_kernel<<<512, 256, 0, stream>>>(aggr, h, Wh_w, Wh_b, w1, b1, w2, b2, eps, out, N);
}

// Round 7
// 152.554 us; speedup vs baseline: 2.0638x; 1.4434x over previous
//
#include <hip/hip_runtime.h>

#define DIM 64
#define NBUCK 256
#define BSHIFT 9
#define BCAP 12288
#define CHUNK 4096

typedef __attribute__((ext_vector_type(4))) float f32x4;
typedef __attribute__((ext_vector_type(8))) short short8;

#define MFMA16(a, b, c) __builtin_amdgcn_mfma_f32_16x16x32_bf16(a, b, c, 0, 0, 0)

template <int CTRL>
__device__ __forceinline__ float qperm(float v) {
    return __int_as_float(__builtin_amdgcn_update_dpp(
        0, __float_as_int(v), CTRL, 0xF, 0xF, true));
}

// split fp32 -> bf16 hi + bf16 lo (truncation; dropped term ~2^-16 rel)
__device__ __forceinline__ void cvt8(const float* f, short8& hi, short8& lo) {
#pragma unroll
    for (int e = 0; e < 8; ++e) {
        const unsigned u = __float_as_uint(f[e]);
        hi[e] = (short)(u >> 16);
        const float hf = __uint_as_float(u & 0xFFFF0000u);
        lo[e] = (short)(__float_as_uint(f[e] - hf) >> 16);
    }
}

// Pre-convert the 4 weight matrices into MFMA B-fragment order.
// wf[(((m*4+t)*2+s)*2+h)*64 + lane] : m in {Wl,Wh,W1,W2}, t=col-tile, s=kstep, h=hi/lo
__global__ __launch_bounds__(256) void prep_kernel(
    const float* __restrict__ Wl, const float* __restrict__ Wh,
    const float* __restrict__ W1, const float* __restrict__ W2,
    short8* __restrict__ wf)
{
    const int tid = threadIdx.x;
    const int m = tid >> 6, l = tid & 63;
    const float* W = (m == 0) ? Wl : (m == 1) ? Wh : (m == 2) ? W1 : W2;
    const int o = l & 15;
    const int kg = (l >> 4) * 8;
#pragma unroll
    for (int t = 0; t < 4; ++t)
#pragma unroll
        for (int s = 0; s < 2; ++s) {
            float f[8];
#pragma unroll
            for (int e = 0; e < 8; ++e)
                f[e] = W[(o + 16 * t) * DIM + 32 * s + kg + e];
            short8 hi, lo;
            cvt8(f, hi, lo);
            const int base = (((m * 4 + t) * 2 + s) * 2);
            wf[(base + 0) * 64 + l] = hi;
            wf[(base + 1) * 64 + l] = lo;
        }
}

// h = x @ Wl^T + b via split-bf16 MFMA. One wave = 16-row strip.
__global__ __launch_bounds__(256, 3) void gemm64_kernel(
    const float* __restrict__ x, const short8* __restrict__ wf,
    const float* __restrict__ bias, float* __restrict__ h, int N)
{
    const int l = threadIdx.x & 63;
    const int gw = blockIdx.x * 4 + (threadIdx.x >> 6);
    const int nw = gridDim.x * 4;
    const int nstrips = (N + 15) >> 4;
    const int lr = l & 15, lk = (l >> 4) * 8, lrow4 = (l >> 4) * 4;

    short8 wh_[4][2], wl_[4][2];
#pragma unroll
    for (int t = 0; t < 4; ++t)
#pragma unroll
        for (int s = 0; s < 2; ++s) {
            wh_[t][s] = wf[(((0 * 4 + t) * 2 + s) * 2 + 0) * 64 + l];
            wl_[t][s] = wf[(((0 * 4 + t) * 2 + s) * 2 + 1) * 64 + l];
        }
    float b4[4];
#pragma unroll
    for (int t = 0; t < 4; ++t) b4[t] = bias[lr + 16 * t];

    for (int strip = gw; strip < nstrips; strip += nw) {
        const int rbase = strip * 16;
        const int arow = min(rbase + lr, N - 1);
        short8 ah[2], al[2];
#pragma unroll
        for (int s = 0; s < 2; ++s) {
            const float4 p0 = *reinterpret_cast<const float4*>(x + (size_t)arow * DIM + 32 * s + lk);
            const float4 p1 = *reinterpret_cast<const float4*>(x + (size_t)arow * DIM + 32 * s + lk + 4);
            float f[8] = {p0.x, p0.y, p0.z, p0.w, p1.x, p1.y, p1.z, p1.w};
            cvt8(f, ah[s], al[s]);
        }
        f32x4 acc[4];
#pragma unroll
        for (int t = 0; t < 4; ++t) acc[t] = (f32x4){b4[t], b4[t], b4[t], b4[t]};
#pragma unroll
        for (int s = 0; s < 2; ++s) {
#pragma unroll
            for (int t = 0; t < 4; ++t) acc[t] = MFMA16(ah[s], wh_[t][s], acc[t]);
#pragma unroll
            for (int t = 0; t < 4; ++t) acc[t] = MFMA16(ah[s], wl_[t][s], acc[t]);
#pragma unroll
            for (int t = 0; t < 4; ++t) acc[t] = MFMA16(al[s], wh_[t][s], acc[t]);
        }
#pragma unroll
        for (int t = 0; t < 4; ++t)
#pragma unroll
            for (int rg = 0; rg < 4; ++rg) {
                const int row = rbase + lrow4 + rg;
                if (row < N) h[(size_t)row * DIM + lr + 16 * t] = acc[t][rg];
            }
    }
}

// fused tail via split-bf16 MFMA: z = (1+eps)*h + aggr@Wh^T+bh ;
// hid = relu(z@W1^T+b1) ; out = hid@W2^T+b2. Wave-local LDS transpose.
__global__ __launch_bounds__(256, 2) void tail_kernel(
    const float* __restrict__ aggr, const float* __restrict__ hres,
    const short8* __restrict__ wf,
    const float* __restrict__ bh, const float* __restrict__ b1,
    const float* __restrict__ b2, const float* __restrict__ eps,
    float* __restrict__ out, int N)
{
    __shared__ float zb[4][16 * 68];
    const int l = threadIdx.x & 63;
    const int w = threadIdx.x >> 6;
    const int gw = blockIdx.x * 4 + w;
    const int nw = gridDim.x * 4;
    const int nstrips = (N + 15) >> 4;
    const int lr = l & 15, lk = (l >> 4) * 8, lrow4 = (l >> 4) * 4;
    float* zw = zb[w];

    // resident hi fragments (96 VGPR); lo fragments streamed per stage
    short8 whh[4][2], w1h[4][2], w2h[4][2];
#pragma unroll
    for (int t = 0; t < 4; ++t)
#pragma unroll
        for (int s = 0; s < 2; ++s) {
            whh[t][s] = wf[(((1 * 4 + t) * 2 + s) * 2 + 0) * 64 + l];
            w1h[t][s] = wf[(((2 * 4 + t) * 2 + s) * 2 + 0) * 64 + l];
            w2h[t][s] = wf[(((3 * 4 + t) * 2 + s) * 2 + 0) * 64 + l];
        }
    float bh4[4], b14[4], b24[4];
#pragma unroll
    for (int t = 0; t < 4; ++t) {
        bh4[t] = bh[lr + 16 * t];
        b14[t] = b1[lr + 16 * t];
        b24[t] = b2[lr + 16 * t];
    }
    const float escale = 1.0f + eps[0];

    for (int strip = gw; strip < nstrips; strip += nw) {
        const int rbase = strip * 16;

        // residual loads (D layout), issued early
        float vh[4][4];
#pragma unroll
        for (int t = 0; t < 4; ++t)
#pragma unroll
            for (int rg = 0; rg < 4; ++rg)
                vh[t][rg] = hres[(size_t)min(rbase + lrow4 + rg, N - 1) * DIM + lr + 16 * t];

        // ---- stage 1: aggr @ Wh^T ----
        const int arow = min(rbase + lr, N - 1);
        short8 ah[2], al[2];
#pragma unroll
        for (int s = 0; s < 2; ++s) {
            const float4 p0 = *reinterpret_cast<const float4*>(aggr + (size_t)arow * DIM + 32 * s + lk);
            const float4 p1 = *reinterpret_cast<const float4*>(aggr + (size_t)arow * DIM + 32 * s + lk + 4);
            float f[8] = {p0.x, p0.y, p0.z, p0.w, p1.x, p1.y, p1.z, p1.w};
            cvt8(f, ah[s], al[s]);
        }
        short8 lo_[4][2];
#pragma unroll
        for (int t = 0; t < 4; ++t)
#pragma unroll
            for (int s = 0; s < 2; ++s)
                lo_[t][s] = wf[(((1 * 4 + t) * 2 + s) * 2 + 1) * 64 + l];
        f32x4 acc[4];
#pragma unroll
        for (int t = 0; t < 4; ++t) acc[t] = (f32x4){bh4[t], bh4[t], bh4[t], bh4[t]};
#pragma unroll
        for (int s = 0; s < 2; ++s) {
#pragma unroll
            for (int t = 0; t < 4; ++t) acc[t] = MFMA16(ah[s], whh[t][s], acc[t]);
#pragma unroll
            for (int t = 0; t < 4; ++t) acc[t] = MFMA16(ah[s], lo_[t][s], acc[t]);
#pragma unroll
            for (int t = 0; t < 4; ++t) acc[t] = MFMA16(al[s], whh[t][s], acc[t]);
        }
        // z epilogue -> LDS (D layout -> transpose buffer)
#pragma unroll
        for (int t = 0; t < 4; ++t)
#pragma unroll
            for (int rg = 0; rg < 4; ++rg)
                zw[(lrow4 + rg) * 68 + lr + 16 * t] = fmaf(escale, vh[t][rg], acc[t][rg]);
        asm volatile("s_waitcnt lgkmcnt(0)" ::: "memory");

        // ---- stage 2: z @ W1^T, relu ----
        short8 zh[2], zl[2];
#pragma unroll
        for (int s = 0; s < 2; ++s) {
            const float4 q0 = *reinterpret_cast<const float4*>(zw + lr * 68 + 32 * s + lk);
            const float4 q1 = *reinterpret_cast<const float4*>(zw + lr * 68 + 32 * s + lk + 4);
            float f[8] = {q0.x, q0.y, q0.z, q0.w, q1.x, q1.y, q1.z, q1.w};
            cvt8(f, zh[s], zl[s]);
        }
#pragma unroll
        for (int t = 0; t < 4; ++t)
#pragma unroll
            for (int s = 0; s < 2; ++s)
                lo_[t][s] = wf[(((2 * 4 + t) * 2 + s) * 2 + 1) * 64 + l];
#pragma unroll
        for (int t = 0; t < 4; ++t) acc[t] = (f32x4){b14[t], b14[t], b14[t], b14[t]};
#pragma unroll
        for (int s = 0; s < 2; ++s) {
#pragma unroll
            for (int t = 0; t < 4; ++t) acc[t] = MFMA16(zh[s], w1h[t][s], acc[t]);
#pragma unroll
            for (int t = 0; t < 4; ++t) acc[t] = MFMA16(zh[s], lo_[t][s], acc[t]);
#pragma unroll
            for (int t = 0; t < 4; ++t) acc[t] = MFMA16(zl[s], w1h[t][s], acc[t]);
        }
#pragma unroll
        for (int t = 0; t < 4; ++t)
#pragma unroll
            for (int rg = 0; rg < 4; ++rg)
                zw[(lrow4 + rg) * 68 + lr + 16 * t] = fmaxf(acc[t][rg], 0.f);
        asm volatile("s_waitcnt lgkmcnt(0)" ::: "memory");

        // ---- stage 3: hid @ W2^T ----
        short8 hh[2], hl[2];
#pragma unroll
        for (int s = 0; s < 2; ++s) {
            const float4 q0 = *reinterpret_cast<const float4*>(zw + lr * 68 + 32 * s + lk);
            const float4 q1 = *reinterpret_cast<const float4*>(zw + lr * 68 + 32 * s + lk + 4);
            float f[8] = {q0.x, q0.y, q0.z, q0.w, q1.x, q1.y, q1.z, q1.w};
            cvt8(f, hh[s], hl[s]);
        }
#pragma unroll
        for (int t = 0; t < 4; ++t)
#pragma unroll
            for (int s = 0; s < 2; ++s)
                lo_[t][s] = wf[(((3 * 4 + t) * 2 + s) * 2 + 1) * 64 + l];
#pragma unroll
        for (int t = 0; t < 4; ++t) acc[t] = (f32x4){b24[t], b24[t], b24[t], b24[t]};
#pragma unroll
        for (int s = 0; s < 2; ++s) {
#pragma unroll
            for (int t = 0; t < 4; ++t) acc[t] = MFMA16(hh[s], w2h[t][s], acc[t]);
#pragma unroll
            for (int t = 0; t < 4; ++t) acc[t] = MFMA16(hh[s], lo_[t][s], acc[t]);
#pragma unroll
            for (int t = 0; t < 4; ++t) acc[t] = MFMA16(hl[s], w2h[t][s], acc[t]);
        }
#pragma unroll
        for (int t = 0; t < 4; ++t)
#pragma unroll
            for (int rg = 0; rg < 4; ++rg) {
                const int row = rbase + lrow4 + rg;
                if (row < N) out[(size_t)row * DIM + lr + 16 * t] = acc[t][rg];
            }
    }
}

__global__ __launch_bounds__(256) void zero256_kernel(int* __restrict__ p) {
    p[threadIdx.x] = 0;
}

__device__ __forceinline__ int wave_incl_scan(int v, int lane) {
#pragma unroll
    for (int off = 1; off < 64; off <<= 1) {
        int t = __shfl_up(v, (unsigned)off, 64);
        if (lane >= off) v += t;
    }
    return v;
}

__global__ __launch_bounds__(256) void bin_kernel(
    const int* __restrict__ ei, const int* __restrict__ sgn,
    int* __restrict__ bcursor, int* __restrict__ records, int E)
{
    const int tid = threadIdx.x;
    const int base = blockIdx.x * CHUNK;
    __shared__ int lcnt[NBUCK];
    __shared__ int lbase[NBUCK];
    lcnt[tid] = 0;
    __syncthreads();
    const int lim = min(CHUNK, E - base);
    for (int k = tid; k < lim; k += 256)
        atomicAdd(&lcnt[ei[base + k] >> BSHIFT], 1);
    __syncthreads();
    const int c = lcnt[tid];
    lbase[tid] = c ? atomicAdd(&bcursor[tid], c) : 0;
    lcnt[tid] = 0;
    __syncthreads();
    for (int k = tid; k < lim; k += 256) {
        const int e = base + k;
        const int r  = ei[e];
        const int cc = ei[E + e];
        const int s  = sgn[e];
        const int b  = r >> BSHIFT;
        const int idx = lbase[b] + atomicAdd(&lcnt[b], 1);
        if (idx < BCAP)
            records[b * BCAP + idx] = cc | (s << 17) | ((r & 511) << 18);
    }
}

__global__ __launch_bounds__(256) void scan256_kernel(
    const int* __restrict__ bcursor, int* __restrict__ csrb,
    int* __restrict__ offsets, int* __restrict__ edata, int N, int E)
{
    const int tid = threadIdx.x, lane = tid & 63, w = tid >> 6;
    const int v = min(bcursor[tid], BCAP);
    const int inc = wave_incl_scan(v, lane);
    __shared__ int wtot[4];
    if (lane == 63) wtot[w] = inc;
    __syncthreads();
    int add = 0;
#pragma unroll
    for (int i = 0; i < 4; ++i)
        if (i < w) add += wtot[i];
    csrb[tid] = add + inc - v;
    if (tid == 0) { offsets[N] = E; edata[E] = 0; }
}

__global__ __launch_bounds__(256) void build_kernel(
    const int* __restrict__ records, const int* __restrict__ bcursor,
    const int* __restrict__ csrb, int* __restrict__ offsets,
    int* __restrict__ edata, int N)
{
    const int b = blockIdx.x;
    const int tid = threadIdx.x, lane = tid & 63, w = tid >> 6;
    const int nbase = b << BSHIFT;
    const int nn = min(512, N - nbase);
    if (nn <= 0) return;
    const int cnt = min(bcursor[b], BCAP);
    const int base_csr = csrb[b];
    const int* rec = records + b * BCAP;

    __shared__ int ncnt[512];
    __shared__ int wtot[8];
    __shared__ int stag[BCAP];

    ncnt[tid] = 0; ncnt[256 + tid] = 0;
    __syncthreads();
    for (int i = tid; i < cnt; i += 256)
        atomicAdd(&ncnt[rec[i] >> 18], 1);
    __syncthreads();
    const int v0 = ncnt[tid], v1 = ncnt[256 + tid];
    const int i0 = wave_incl_scan(v0, lane);
    if (lane == 63) wtot[w] = i0;
    const int i1 = wave_incl_scan(v1, lane);
    if (lane == 63) wtot[4 + w] = i1;
    __syncthreads();
    int a0 = 0, a1 = 0;
#pragma unroll
    for (int i = 0; i < 4; ++i) {
        if (i < w) { a0 += wtot[i]; a1 += wtot[4 + i]; }
    }
    const int half = wtot[0] + wtot[1] + wtot[2] + wtot[3];
    const int e0 = a0 + i0 - v0;
    const int e1 = half + a1 + i1 - v1;
    if (tid < nn)       offsets[nbase + tid]       = base_csr + e0;
    if (256 + tid < nn) offsets[nbase + 256 + tid] = base_csr + e1;
    __syncthreads();
    ncnt[tid] = e0; ncnt[256 + tid] = e1;
    __syncthreads();
    for (int i = tid; i < cnt; i += 256) {
        const int rcd = rec[i];
        const int p = atomicAdd(&ncnt[rcd >> 18], 1);
        stag[p] = (rcd & 0x1FFFF) | (((rcd >> 17) & 1) << 20);
    }
    __syncthreads();
    for (int i = tid; i < cnt; i += 256)
        edata[base_csr + i] = stag[i];
}

// 4 nodes per wave; 16 lanes per node; lane holds float4 of the feature row.
__global__ __launch_bounds__(256) void attn_kernel(
    const float* __restrict__ h, const int* __restrict__ offsets,
    const int* __restrict__ edata, const float* __restrict__ sign_tab,
    float* __restrict__ aggr, int n)
{
    const int lane = threadIdx.x & 63;
    const int gl   = lane & 15;
    const int node = blockIdx.x * 16 + ((threadIdx.x >> 6) << 2) + (lane >> 4);
    const bool alive = node < n;

    int beg = 0, deg = 0;
    if (alive) {
        beg = offsets[node];
        deg = offsets[node + 1] - beg;
    }
    float4 hi = make_float4(0.f, 0.f, 0.f, 0.f);
    if (alive) hi = *reinterpret_cast<const float4*>(h + (size_t)node * DIM + gl * 4);

    const float4 s0 = *reinterpret_cast<const float4*>(sign_tab + (gl & 3) * 4);
    const float4 s1 = *reinterpret_cast<const float4*>(sign_tab + 16 + (gl & 3) * 4);
    const float4 hs0 = make_float4(hi.x * s0.x, hi.y * s0.y, hi.z * s0.z, hi.w * s0.w);
    const float4 hs1 = make_float4(hi.x * s1.x, hi.y * s1.y, hi.z * s1.z, hi.w * s1.w);

    const int degm1 = deg - 1;
    int maxdeg = max(deg, __shfl_xor(deg, 16, 64));
    maxdeg = max(maxdeg, __shfl_xor(maxdeg, 32, 64));

    float den = 0.f;
    float4 msg = make_float4(0.f, 0.f, 0.f, 0.f);

    for (int e = 0; e < maxdeg; e += 4) {
        int idx[4], pk[4];
#pragma unroll
        for (int u = 0; u < 4; ++u) idx[u] = max(0, min(e + u, degm1));
#pragma unroll
        for (int u = 0; u < 4; ++u) pk[u] = edata[beg + idx[u]];

        float4 hj[4];
#pragma unroll
        for (int u = 0; u < 4; ++u) {
            const int col = pk[u] & 0xFFFFF;
            hj[u] = *reinterpret_cast<const float4*>(h + (size_t)col * DIM + gl * 4);
        }

        float sc[4];
#pragma unroll
        for (int u = 0; u < 4; ++u) {
            const float4 wv = (pk[u] >> 20) ? hs1 : hs0;
            float s = wv.x * hj[u].x;
            s = fmaf(wv.y, hj[u].y, s);
            s = fmaf(wv.z, hj[u].z, s);
            s = fmaf(wv.w, hj[u].w, s);
            sc[u] = s;
        }
#pragma unroll
        for (int u = 0; u < 4; ++u) sc[u] += qperm<0xB1>(sc[u]);
#pragma unroll
        for (int u = 0; u < 4; ++u) sc[u] += qperm<0x4E>(sc[u]);

#pragma unroll
        for (int u = 0; u < 4; ++u) {
            const float ex = (e + u < deg) ? __expf(sc[u]) : 0.f;
            den += ex;
            msg.x = fmaf(ex, hj[u].x, msg.x);
            msg.y = fmaf(ex, hj[u].y, msg.y);
            msg.z = fmaf(ex, hj[u].z, msg.z);
            msg.w = fmaf(ex, hj[u].w, msg.w);
        }
    }

    if (alive) {
        const float inv = 1.0f / (den + 1e-16f);
        float4 o = make_float4(msg.x * inv, msg.y * inv, msg.z * inv, msg.w * inv);
        *reinterpret_cast<float4*>(aggr + (size_t)node * DIM + gl * 4) = o;
    }
}

extern "C" void kernel_launch(void* const* d_in, const int* in_sizes, int n_in,
                              void* d_out, int out_size, void* d_ws, size_t ws_size,
                              hipStream_t stream) {
    const float* x        = (const float*)d_in[0];
    const int*   ei       = (const int*)d_in[1];
    const int*   esign    = (const int*)d_in[2];
    const float* Wl_w     = (const float*)d_in[3];
    const float* Wl_b     = (const float*)d_in[4];
    const float* sign_tab = (const float*)d_in[5];
    const float* Wh_w     = (const float*)d_in[6];
    const float* Wh_b     = (const float*)d_in[7];
    const float* w1       = (const float*)d_in[8];
    const float* b1       = (const float*)d_in[9];
    const float* w2       = (const float*)d_in[10];
    const float* b2       = (const float*)d_in[11];
    const float* eps      = (const float*)d_in[12];
    float* out = (float*)d_out;

    const int N = in_sizes[0] / DIM;
    const int E = in_sizes[2];

    float* h       = (float*)d_ws;
    float* aggr    = h + (size_t)N * DIM;
    int*   records = (int*)aggr;                 // alias: dead before attn writes aggr
    int*   edata   = (int*)(aggr + (size_t)N * DIM);
    int*   bcursor = edata + (E + 1);
    int*   csrb    = bcursor + NBUCK;
    int*   offsets = csrb + NBUCK;               // N+1 ints
    short8* wf     = (short8*)(offsets + ((N + 1 + 3) & ~3));  // 16KB, 16B-aligned

    // weight fragment prep (hi/lo bf16, B-frag order)
    prep_kernel<<<1, 256, 0, stream>>>(Wl_w, Wh_w, w1, w2, wf);

    // h = x @ Wl^T + Wl_b  (MFMA)
    gemm64_kernel<<<512, 256, 0, stream>>>(x, wf, Wl_b, h, N);

    // bucketed counting-sort CSR build
    zero256_kernel<<<1, 256, 0, stream>>>(bcursor);
    bin_kernel<<<(E + CHUNK - 1) / CHUNK, 256, 0, stream>>>(ei, esign, bcursor, records, E);
    scan256_kernel<<<1, 256, 0, stream>>>(bcursor, csrb, offsets, edata, N, E);
    build_kernel<<<NBUCK, 256, 0, stream>>>(records, bcursor, csrb, offsets, edata, N);

    // segment softmax + aggregation
    attn_kernel<<<(N + 15) / 16, 256, 0, stream>>>(h, offsets, edata, sign_tab, aggr, N);

    // fused tail (MFMA): z -> relu mlp -> out
    tail_kernel<<<512, 256, 0, stream>>>(aggr, h, wf, Wh_b, b1, b2, eps, out, N);
}

// Round 8
// 132.871 us; speedup vs baseline: 2.3695x; 1.1481x over previous
//
#include <hip/hip_runtime.h>

#define DIM 64
#define NBUCK 256
#define BSHIFT 9
#define BCAP 12288
#define CHUNK 4096

typedef __attribute__((ext_vector_type(4))) float f32x4;
typedef __attribute__((ext_vector_type(8))) short short8;
typedef __attribute__((ext_vector_type(4))) unsigned short ushort4v;

#define MFMA16(a, b, c) __builtin_amdgcn_mfma_f32_16x16x32_bf16(a, b, c, 0, 0, 0)

template <int CTRL>
__device__ __forceinline__ float qperm(float v) {
    return __int_as_float(__builtin_amdgcn_update_dpp(
        0, __float_as_int(v), CTRL, 0xF, 0xF, true));
}

// split fp32 -> bf16 hi + bf16 lo (truncation; dropped term ~2^-16 rel)
__device__ __forceinline__ void cvt8(const float* f, short8& hi, short8& lo) {
#pragma unroll
    for (int e = 0; e < 8; ++e) {
        const unsigned u = __float_as_uint(f[e]);
        hi[e] = (short)(u >> 16);
        const float hf = __uint_as_float(u & 0xFFFF0000u);
        lo[e] = (short)(__float_as_uint(f[e] - hf) >> 16);
    }
}

__device__ __forceinline__ unsigned short bf16rne(float f) {
    const unsigned u = __float_as_uint(f);
    return (unsigned short)((u + 0x7FFFu + ((u >> 16) & 1u)) >> 16);
}

// Pre-convert the 4 weight matrices into MFMA B-fragment order.
__global__ __launch_bounds__(256) void prep_kernel(
    const float* __restrict__ Wl, const float* __restrict__ Wh,
    const float* __restrict__ W1, const float* __restrict__ W2,
    short8* __restrict__ wf)
{
    const int tid = threadIdx.x;
    const int m = tid >> 6, l = tid & 63;
    const float* W = (m == 0) ? Wl : (m == 1) ? Wh : (m == 2) ? W1 : W2;
    const int o = l & 15;
    const int kg = (l >> 4) * 8;
#pragma unroll
    for (int t = 0; t < 4; ++t)
#pragma unroll
        for (int s = 0; s < 2; ++s) {
            float f[8];
#pragma unroll
            for (int e = 0; e < 8; ++e)
                f[e] = W[(o + 16 * t) * DIM + 32 * s + kg + e];
            short8 hi, lo;
            cvt8(f, hi, lo);
            const int base = (((m * 4 + t) * 2 + s) * 2);
            wf[(base + 0) * 64 + l] = hi;
            wf[(base + 1) * 64 + l] = lo;
        }
}

// h = x @ Wl^T + b via split-bf16 MFMA; also emits bf16 mirror hb for gathers.
__global__ __launch_bounds__(256, 3) void gemm64_kernel(
    const float* __restrict__ x, const short8* __restrict__ wf,
    const float* __restrict__ bias, float* __restrict__ h,
    unsigned short* __restrict__ hb, int N)
{
    const int l = threadIdx.x & 63;
    const int gw = blockIdx.x * 4 + (threadIdx.x >> 6);
    const int nw = gridDim.x * 4;
    const int nstrips = (N + 15) >> 4;
    const int lr = l & 15, lk = (l >> 4) * 8, lrow4 = (l >> 4) * 4;

    short8 wh_[4][2], wl_[4][2];
#pragma unroll
    for (int t = 0; t < 4; ++t)
#pragma unroll
        for (int s = 0; s < 2; ++s) {
            wh_[t][s] = wf[(((0 * 4 + t) * 2 + s) * 2 + 0) * 64 + l];
            wl_[t][s] = wf[(((0 * 4 + t) * 2 + s) * 2 + 1) * 64 + l];
        }
    float b4[4];
#pragma unroll
    for (int t = 0; t < 4; ++t) b4[t] = bias[lr + 16 * t];

    for (int strip = gw; strip < nstrips; strip += nw) {
        const int rbase = strip * 16;
        const int arow = min(rbase + lr, N - 1);
        short8 ah[2], al[2];
#pragma unroll
        for (int s = 0; s < 2; ++s) {
            const float4 p0 = *reinterpret_cast<const float4*>(x + (size_t)arow * DIM + 32 * s + lk);
            const float4 p1 = *reinterpret_cast<const float4*>(x + (size_t)arow * DIM + 32 * s + lk + 4);
            float f[8] = {p0.x, p0.y, p0.z, p0.w, p1.x, p1.y, p1.z, p1.w};
            cvt8(f, ah[s], al[s]);
        }
        f32x4 acc[4];
#pragma unroll
        for (int t = 0; t < 4; ++t) acc[t] = (f32x4){b4[t], b4[t], b4[t], b4[t]};
#pragma unroll
        for (int s = 0; s < 2; ++s) {
#pragma unroll
            for (int t = 0; t < 4; ++t) acc[t] = MFMA16(ah[s], wh_[t][s], acc[t]);
#pragma unroll
            for (int t = 0; t < 4; ++t) acc[t] = MFMA16(ah[s], wl_[t][s], acc[t]);
#pragma unroll
            for (int t = 0; t < 4; ++t) acc[t] = MFMA16(al[s], wh_[t][s], acc[t]);
        }
#pragma unroll
        for (int t = 0; t < 4; ++t)
#pragma unroll
            for (int rg = 0; rg < 4; ++rg) {
                const int row = rbase + lrow4 + rg;
                if (row < N) {
                    h[(size_t)row * DIM + lr + 16 * t] = acc[t][rg];
                    hb[(size_t)row * DIM + lr + 16 * t] = bf16rne(acc[t][rg]);
                }
            }
    }
}

// fused tail via split-bf16 MFMA (unchanged from round 6)
__global__ __launch_bounds__(256, 2) void tail_kernel(
    const float* __restrict__ aggr, const float* __restrict__ hres,
    const short8* __restrict__ wf,
    const float* __restrict__ bh, const float* __restrict__ b1,
    const float* __restrict__ b2, const float* __restrict__ eps,
    float* __restrict__ out, int N)
{
    __shared__ float zb[4][16 * 68];
    const int l = threadIdx.x & 63;
    const int w = threadIdx.x >> 6;
    const int gw = blockIdx.x * 4 + w;
    const int nw = gridDim.x * 4;
    const int nstrips = (N + 15) >> 4;
    const int lr = l & 15, lk = (l >> 4) * 8, lrow4 = (l >> 4) * 4;
    float* zw = zb[w];

    short8 whh[4][2], w1h[4][2], w2h[4][2];
#pragma unroll
    for (int t = 0; t < 4; ++t)
#pragma unroll
        for (int s = 0; s < 2; ++s) {
            whh[t][s] = wf[(((1 * 4 + t) * 2 + s) * 2 + 0) * 64 + l];
            w1h[t][s] = wf[(((2 * 4 + t) * 2 + s) * 2 + 0) * 64 + l];
            w2h[t][s] = wf[(((3 * 4 + t) * 2 + s) * 2 + 0) * 64 + l];
        }
    float bh4[4], b14[4], b24[4];
#pragma unroll
    for (int t = 0; t < 4; ++t) {
        bh4[t] = bh[lr + 16 * t];
        b14[t] = b1[lr + 16 * t];
        b24[t] = b2[lr + 16 * t];
    }
    const float escale = 1.0f + eps[0];

    for (int strip = gw; strip < nstrips; strip += nw) {
        const int rbase = strip * 16;

        float vh[4][4];
#pragma unroll
        for (int t = 0; t < 4; ++t)
#pragma unroll
            for (int rg = 0; rg < 4; ++rg)
                vh[t][rg] = hres[(size_t)min(rbase + lrow4 + rg, N - 1) * DIM + lr + 16 * t];

        // ---- stage 1: aggr @ Wh^T ----
        const int arow = min(rbase + lr, N - 1);
        short8 ah[2], al[2];
#pragma unroll
        for (int s = 0; s < 2; ++s) {
            const float4 p0 = *reinterpret_cast<const float4*>(aggr + (size_t)arow * DIM + 32 * s + lk);
            const float4 p1 = *reinterpret_cast<const float4*>(aggr + (size_t)arow * DIM + 32 * s + lk + 4);
            float f[8] = {p0.x, p0.y, p0.z, p0.w, p1.x, p1.y, p1.z, p1.w};
            cvt8(f, ah[s], al[s]);
        }
        short8 lo_[4][2];
#pragma unroll
        for (int t = 0; t < 4; ++t)
#pragma unroll
            for (int s = 0; s < 2; ++s)
                lo_[t][s] = wf[(((1 * 4 + t) * 2 + s) * 2 + 1) * 64 + l];
        f32x4 acc[4];
#pragma unroll
        for (int t = 0; t < 4; ++t) acc[t] = (f32x4){bh4[t], bh4[t], bh4[t], bh4[t]};
#pragma unroll
        for (int s = 0; s < 2; ++s) {
#pragma unroll
            for (int t = 0; t < 4; ++t) acc[t] = MFMA16(ah[s], whh[t][s], acc[t]);
#pragma unroll
            for (int t = 0; t < 4; ++t) acc[t] = MFMA16(ah[s], lo_[t][s], acc[t]);
#pragma unroll
            for (int t = 0; t < 4; ++t) acc[t] = MFMA16(al[s], whh[t][s], acc[t]);
        }
#pragma unroll
        for (int t = 0; t < 4; ++t)
#pragma unroll
            for (int rg = 0; rg < 4; ++rg)
                zw[(lrow4 + rg) * 68 + lr + 16 * t] = fmaf(escale, vh[t][rg], acc[t][rg]);
        asm volatile("s_waitcnt lgkmcnt(0)" ::: "memory");

        // ---- stage 2: z @ W1^T, relu ----
        short8 zh[2], zl[2];
#pragma unroll
        for (int s = 0; s < 2; ++s) {
            const float4 q0 = *reinterpret_cast<const float4*>(zw + lr * 68 + 32 * s + lk);
            const float4 q1 = *reinterpret_cast<const float4*>(zw + lr * 68 + 32 * s + lk + 4);
            float f[8] = {q0.x, q0.y, q0.z, q0.w, q1.x, q1.y, q1.z, q1.w};
            cvt8(f, zh[s], zl[s]);
        }
#pragma unroll
        for (int t = 0; t < 4; ++t)
#pragma unroll
            for (int s = 0; s < 2; ++s)
                lo_[t][s] = wf[(((2 * 4 + t) * 2 + s) * 2 + 1) * 64 + l];
#pragma unroll
        for (int t = 0; t < 4; ++t) acc[t] = (f32x4){b14[t], b14[t], b14[t], b14[t]};
#pragma unroll
        for (int s = 0; s < 2; ++s) {
#pragma unroll
            for (int t = 0; t < 4; ++t) acc[t] = MFMA16(zh[s], w1h[t][s], acc[t]);
#pragma unroll
            for (int t = 0; t < 4; ++t) acc[t] = MFMA16(zh[s], lo_[t][s], acc[t]);
#pragma unroll
            for (int t = 0; t < 4; ++t) acc[t] = MFMA16(zl[s], w1h[t][s], acc[t]);
        }
#pragma unroll
        for (int t = 0; t < 4; ++t)
#pragma unroll
            for (int rg = 0; rg < 4; ++rg)
                zw[(lrow4 + rg) * 68 + lr + 16 * t] = fmaxf(acc[t][rg], 0.f);
        asm volatile("s_waitcnt lgkmcnt(0)" ::: "memory");

        // ---- stage 3: hid @ W2^T ----
        short8 hh[2], hl[2];
#pragma unroll
        for (int s = 0; s < 2; ++s) {
            const float4 q0 = *reinterpret_cast<const float4*>(zw + lr * 68 + 32 * s + lk);
            const float4 q1 = *reinterpret_cast<const float4*>(zw + lr * 68 + 32 * s + lk + 4);
            float f[8] = {q0.x, q0.y, q0.z, q0.w, q1.x, q1.y, q1.z, q1.w};
            cvt8(f, hh[s], hl[s]);
        }
#pragma unroll
        for (int t = 0; t < 4; ++t)
#pragma unroll
            for (int s = 0; s < 2; ++s)
                lo_[t][s] = wf[(((3 * 4 + t) * 2 + s) * 2 + 1) * 64 + l];
#pragma unroll
        for (int t = 0; t < 4; ++t) acc[t] = (f32x4){b24[t], b24[t], b24[t], b24[t]};
#pragma unroll
        for (int s = 0; s < 2; ++s) {
#pragma unroll
            for (int t = 0; t < 4; ++t) acc[t] = MFMA16(hh[s], w2h[t][s], acc[t]);
#pragma unroll
            for (int t = 0; t < 4; ++t) acc[t] = MFMA16(hh[s], lo_[t][s], acc[t]);
#pragma unroll
            for (int t = 0; t < 4; ++t) acc[t] = MFMA16(hl[s], w2h[t][s], acc[t]);
        }
#pragma unroll
        for (int t = 0; t < 4; ++t)
#pragma unroll
            for (int rg = 0; rg < 4; ++rg) {
                const int row = rbase + lrow4 + rg;
                if (row < N) out[(size_t)row * DIM + lr + 16 * t] = acc[t][rg];
            }
    }
}

__global__ __launch_bounds__(256) void zero256_kernel(int* __restrict__ p) {
    p[threadIdx.x] = 0;
}

__device__ __forceinline__ int wave_incl_scan(int v, int lane) {
#pragma unroll
    for (int off = 1; off < 64; off <<= 1) {
        int t = __shfl_up(v, (unsigned)off, 64);
        if (lane >= off) v += t;
    }
    return v;
}

__global__ __launch_bounds__(256) void bin_kernel(
    const int* __restrict__ ei, const int* __restrict__ sgn,
    int* __restrict__ bcursor, int* __restrict__ records, int E)
{
    const int tid = threadIdx.x;
    const int base = blockIdx.x * CHUNK;
    __shared__ int lcnt[NBUCK];
    __shared__ int lbase[NBUCK];
    lcnt[tid] = 0;
    __syncthreads();
    const int lim = min(CHUNK, E - base);
    for (int k = tid; k < lim; k += 256)
        atomicAdd(&lcnt[ei[base + k] >> BSHIFT], 1);
    __syncthreads();
    const int c = lcnt[tid];
    lbase[tid] = c ? atomicAdd(&bcursor[tid], c) : 0;
    lcnt[tid] = 0;
    __syncthreads();
    for (int k = tid; k < lim; k += 256) {
        const int e = base + k;
        const int r  = ei[e];
        const int cc = ei[E + e];
        const int s  = sgn[e];
        const int b  = r >> BSHIFT;
        const int idx = lbase[b] + atomicAdd(&lcnt[b], 1);
        if (idx < BCAP)
            records[b * BCAP + idx] = cc | (s << 17) | ((r & 511) << 18);
    }
}

__global__ __launch_bounds__(256) void scan256_kernel(
    const int* __restrict__ bcursor, int* __restrict__ csrb,
    int* __restrict__ offsets, int* __restrict__ edata, int N, int E)
{
    const int tid = threadIdx.x, lane = tid & 63, w = tid >> 6;
    const int v = min(bcursor[tid], BCAP);
    const int inc = wave_incl_scan(v, lane);
    __shared__ int wtot[4];
    if (lane == 63) wtot[w] = inc;
    __syncthreads();
    int add = 0;
#pragma unroll
    for (int i = 0; i < 4; ++i)
        if (i < w) add += wtot[i];
    csrb[tid] = add + inc - v;
    if (tid == 0) { offsets[N] = E; edata[E] = 0; }
}

__global__ __launch_bounds__(256) void build_kernel(
    const int* __restrict__ records, const int* __restrict__ bcursor,
    const int* __restrict__ csrb, int* __restrict__ offsets,
    int* __restrict__ edata, int N)
{
    const int b = blockIdx.x;
    const int tid = threadIdx.x, lane = tid & 63, w = tid >> 6;
    const int nbase = b << BSHIFT;
    const int nn = min(512, N - nbase);
    if (nn <= 0) return;
    const int cnt = min(bcursor[b], BCAP);
    const int base_csr = csrb[b];
    const int* rec = records + b * BCAP;

    __shared__ int ncnt[512];
    __shared__ int wtot[8];
    __shared__ int stag[BCAP];

    ncnt[tid] = 0; ncnt[256 + tid] = 0;
    __syncthreads();
    for (int i = tid; i < cnt; i += 256)
        atomicAdd(&ncnt[rec[i] >> 18], 1);
    __syncthreads();
    const int v0 = ncnt[tid], v1 = ncnt[256 + tid];
    const int i0 = wave_incl_scan(v0, lane);
    if (lane == 63) wtot[w] = i0;
    const int i1 = wave_incl_scan(v1, lane);
    if (lane == 63) wtot[4 + w] = i1;
    __syncthreads();
    int a0 = 0, a1 = 0;
#pragma unroll
    for (int i = 0; i < 4; ++i) {
        if (i < w) { a0 += wtot[i]; a1 += wtot[4 + i]; }
    }
    const int half = wtot[0] + wtot[1] + wtot[2] + wtot[3];
    const int e0 = a0 + i0 - v0;
    const int e1 = half + a1 + i1 - v1;
    if (tid < nn)       offsets[nbase + tid]       = base_csr + e0;
    if (256 + tid < nn) offsets[nbase + 256 + tid] = base_csr + e1;
    __syncthreads();
    ncnt[tid] = e0; ncnt[256 + tid] = e1;
    __syncthreads();
    for (int i = tid; i < cnt; i += 256) {
        const int rcd = rec[i];
        const int p = atomicAdd(&ncnt[rcd >> 18], 1);
        stag[p] = (rcd & 0x1FFFF) | (((rcd >> 17) & 1) << 20);
    }
    __syncthreads();
    for (int i = tid; i < cnt; i += 256)
        edata[base_csr + i] = stag[i];
}

// 4 nodes per wave; 16 lanes per node; bf16 gathers (8 B/lane).
__global__ __launch_bounds__(256) void attn_kernel(
    const float* __restrict__ h, const unsigned short* __restrict__ hb,
    const int* __restrict__ offsets, const int* __restrict__ edata,
    const float* __restrict__ sign_tab, float* __restrict__ aggr, int n)
{
    const int lane = threadIdx.x & 63;
    const int gl   = lane & 15;
    const int node = blockIdx.x * 16 + ((threadIdx.x >> 6) << 2) + (lane >> 4);
    const bool alive = node < n;

    int beg = 0, deg = 0;
    if (alive) {
        beg = offsets[node];
        deg = offsets[node + 1] - beg;
    }
    float4 hi = make_float4(0.f, 0.f, 0.f, 0.f);
    if (alive) hi = *reinterpret_cast<const float4*>(h + (size_t)node * DIM + gl * 4);

    const float4 s0 = *reinterpret_cast<const float4*>(sign_tab + (gl & 3) * 4);
    const float4 s1 = *reinterpret_cast<const float4*>(sign_tab + 16 + (gl & 3) * 4);
    const float4 hs0 = make_float4(hi.x * s0.x, hi.y * s0.y, hi.z * s0.z, hi.w * s0.w);
    const float4 hs1 = make_float4(hi.x * s1.x, hi.y * s1.y, hi.z * s1.z, hi.w * s1.w);

    const int degm1 = deg - 1;
    int maxdeg = max(deg, __shfl_xor(deg, 16, 64));
    maxdeg = max(maxdeg, __shfl_xor(maxdeg, 32, 64));

    float den = 0.f;
    float4 msg = make_float4(0.f, 0.f, 0.f, 0.f);

    for (int e = 0; e < maxdeg; e += 4) {
        int idx[4], pk[4];
#pragma unroll
        for (int u = 0; u < 4; ++u) idx[u] = max(0, min(e + u, degm1));
#pragma unroll
        for (int u = 0; u < 4; ++u) pk[u] = edata[beg + idx[u]];

        float4 hj[4];
#pragma unroll
        for (int u = 0; u < 4; ++u) {
            const int col = pk[u] & 0xFFFFF;
            const ushort4v v = *reinterpret_cast<const ushort4v*>(hb + (size_t)col * DIM + gl * 4);
            hj[u].x = __uint_as_float(((unsigned)v.x) << 16);
            hj[u].y = __uint_as_float(((unsigned)v.y) << 16);
            hj[u].z = __uint_as_float(((unsigned)v.z) << 16);
            hj[u].w = __uint_as_float(((unsigned)v.w) << 16);
        }

        float sc[4];
#pragma unroll
        for (int u = 0; u < 4; ++u) {
            const float4 wv = (pk[u] >> 20) ? hs1 : hs0;
            float s = wv.x * hj[u].x;
            s = fmaf(wv.y, hj[u].y, s);
            s = fmaf(wv.z, hj[u].z, s);
            s = fmaf(wv.w, hj[u].w, s);
            sc[u] = s;
        }
#pragma unroll
        for (int u = 0; u < 4; ++u) sc[u] += qperm<0xB1>(sc[u]);
#pragma unroll
        for (int u = 0; u < 4; ++u) sc[u] += qperm<0x4E>(sc[u]);

#pragma unroll
        for (int u = 0; u < 4; ++u) {
            const float ex = (e + u < deg) ? __expf(sc[u]) : 0.f;
            den += ex;
            msg.x = fmaf(ex, hj[u].x, msg.x);
            msg.y = fmaf(ex, hj[u].y, msg.y);
            msg.z = fmaf(ex, hj[u].z, msg.z);
            msg.w = fmaf(ex, hj[u].w, msg.w);
        }
    }

    if (alive) {
        const float inv = 1.0f / (den + 1e-16f);
        float4 o = make_float4(msg.x * inv, msg.y * inv, msg.z * inv, msg.w * inv);
        *reinterpret_cast<float4*>(aggr + (size_t)node * DIM + gl * 4) = o;
    }
}

extern "C" void kernel_launch(void* const* d_in, const int* in_sizes, int n_in,
                              void* d_out, int out_size, void* d_ws, size_t ws_size,
                              hipStream_t stream) {
    const float* x        = (const float*)d_in[0];
    const int*   ei       = (const int*)d_in[1];
    const int*   esign    = (const int*)d_in[2];
    const float* Wl_w     = (const float*)d_in[3];
    const float* Wl_b     = (const float*)d_in[4];
    const float* sign_tab = (const float*)d_in[5];
    const float* Wh_w     = (const float*)d_in[6];
    const float* Wh_b     = (const float*)d_in[7];
    const float* w1       = (const float*)d_in[8];
    const float* b1       = (const float*)d_in[9];
    const float* w2       = (const float*)d_in[10];
    const float* b2       = (const float*)d_in[11];
    const float* eps      = (const float*)d_in[12];
    float* out = (float*)d_out;

    const int N = in_sizes[0] / DIM;
    const int E = in_sizes[2];

    float* h       = (float*)d_ws;
    float* aggr    = h + (size_t)N * DIM;
    int*   records = (int*)aggr;                 // alias: dead before attn writes aggr
    int*   edata   = (int*)(aggr + (size_t)N * DIM);
    int*   bcursor = edata + (E + 1);
    int*   csrb    = bcursor + NBUCK;
    int*   offsets = csrb + NBUCK;               // N+1 ints
    short8* wf     = (short8*)(offsets + ((N + 1 + 3) & ~3));  // 16KB, 16B-aligned
    unsigned short* hb = (unsigned short*)d_out; // bf16 mirror: d_out is dead
                                                 // scratch until tail overwrites it

    // weight fragment prep (hi/lo bf16, B-frag order)
    prep_kernel<<<1, 256, 0, stream>>>(Wl_w, Wh_w, w1, w2, wf);

    // h = x @ Wl^T + Wl_b  (MFMA) + bf16 mirror
    gemm64_kernel<<<512, 256, 0, stream>>>(x, wf, Wl_b, h, hb, N);

    // bucketed counting-sort CSR build
    zero256_kernel<<<1, 256, 0, stream>>>(bcursor);
    bin_kernel<<<(E + CHUNK - 1) / CHUNK, 256, 0, stream>>>(ei, esign, bcursor, records, E);
    scan256_kernel<<<1, 256, 0, stream>>>(bcursor, csrb, offsets, edata, N, E);
    build_kernel<<<NBUCK, 256, 0, stream>>>(records, bcursor, csrb, offsets, edata, N);

    // segment softmax + aggregation (bf16 gathers)
    attn_kernel<<<(N + 15) / 16, 256, 0, stream>>>(h, hb, offsets, edata, sign_tab, aggr, N);

    // fused tail (MFMA): z -> relu mlp -> out
    tail_kernel<<<512, 256, 0, stream>>>(aggr, h, wf, Wh_b, b1, b2, eps, out, N);
}